// Round 7
// baseline (138.939 us; speedup 1.0000x reference)
//
#include <hip/hip_runtime.h>

#define BB 2
#define HH 48
#define WW 48
#define CC 192
#define NHEADS 6
#define HD 32
#define KK 9
#define FF 486
#define NPIX (BB*HH*WW)   // 4608
#define SCALE 0.17677669529663687f  // 1/sqrt(32)

typedef __bf16 bf16;
typedef __attribute__((ext_vector_type(4))) __bf16 bf16x4;
typedef __attribute__((ext_vector_type(8))) __bf16 bf16x8;
typedef __attribute__((ext_vector_type(4))) float f32x4;

#define BM 128
#define BN 64
#define KD 192
#define LDA 200   // padded LDS row stride in bf16 (400 B, 16B-aligned, bank-balanced)

// ---------------------------------------------------------------------------
// MFMA GEMM core (unchanged from round 6): OUT[M][N] = X[M][192] * W[N][192]^T
// ---------------------------------------------------------------------------
__device__ __forceinline__ void gemm_core(
    const float* __restrict__ X, const float* __restrict__ W,
    const float* __restrict__ bias, float* __restrict__ OUT,
    int m0, int n0, int Ndim,
    bf16 (*As)[LDA], bf16 (*Bs)[LDA])
{
    const int tid = threadIdx.x;

    #pragma unroll
    for (int i = 0; i < 24; ++i) {
        const int f = tid + i * 256;
        const int row = f / 48, colf = f % 48;
        const float4 xv = *(const float4*)(X + (size_t)(m0 + row) * KD + colf * 4);
        bf16x4 t = { (__bf16)xv.x, (__bf16)xv.y, (__bf16)xv.z, (__bf16)xv.w };
        *(bf16x4*)(&As[row][colf * 4]) = t;
    }
    #pragma unroll
    for (int i = 0; i < 12; ++i) {
        const int f = tid + i * 256;
        const int row = f / 48, colf = f % 48;
        float4 wv = make_float4(0.f, 0.f, 0.f, 0.f);
        if (n0 + row < Ndim)
            wv = *(const float4*)(W + (size_t)(n0 + row) * KD + colf * 4);
        bf16x4 t = { (__bf16)wv.x, (__bf16)wv.y, (__bf16)wv.z, (__bf16)wv.w };
        *(bf16x4*)(&Bs[row][colf * 4]) = t;
    }
    __syncthreads();

    const int wave = tid >> 6, lane = tid & 63;
    const int wm = (wave >> 1) * 64;
    const int wn = (wave & 1) * 32;
    const int lrow = lane & 15;
    const int lk   = (lane >> 4) * 8;

    f32x4 acc[4][2] = {};
    #pragma unroll
    for (int ks = 0; ks < 6; ++ks) {
        bf16x8 bfr[2];
        #pragma unroll
        for (int j = 0; j < 2; ++j)
            bfr[j] = *(const bf16x8*)(&Bs[wn + j * 16 + lrow][ks * 32 + lk]);
        #pragma unroll
        for (int i = 0; i < 4; ++i) {
            bf16x8 afr = *(const bf16x8*)(&As[wm + i * 16 + lrow][ks * 32 + lk]);
            #pragma unroll
            for (int j = 0; j < 2; ++j)
                acc[i][j] = __builtin_amdgcn_mfma_f32_16x16x32_bf16(afr, bfr[j], acc[i][j], 0, 0, 0);
        }
    }

    const int crow = (lane >> 4) * 4;
    #pragma unroll
    for (int j = 0; j < 2; ++j) {
        const int col = n0 + wn + j * 16 + lrow;
        if (col < Ndim) {
            const float bv = bias ? bias[col] : 0.f;
            #pragma unroll
            for (int i = 0; i < 4; ++i) {
                #pragma unroll
                for (int r = 0; r < 4; ++r) {
                    const int row = m0 + wm + i * 16 + crow + r;
                    OUT[(size_t)row * Ndim + col] = acc[i][j][r] + bv;
                }
            }
        }
    }
}

__global__ __launch_bounds__(256) void gemm_va_kernel(
    const float* __restrict__ x, const float* __restrict__ vw,
    const float* __restrict__ aw, const float* __restrict__ ab,
    float* __restrict__ v, float* __restrict__ a)
{
    __shared__ bf16 As[BM][LDA];
    __shared__ bf16 Bs[BN][LDA];
    const int m0 = blockIdx.x * BM;
    const int by = blockIdx.y;
    if (by < 3) gemm_core(x, vw, nullptr, v, m0, by * 64, CC, As, Bs);
    else        gemm_core(x, aw, ab,      a, m0, (by - 3) * 64, FF, As, Bs);
}

// ---------------------------------------------------------------------------
// attn8: 8 pixels per 256-thread block. Shared 3x10 v-patch + 8 logit rows.
// ---------------------------------------------------------------------------
__global__ __launch_bounds__(256) void attn8_kernel(
    const float* __restrict__ v, const float* __restrict__ a,
    float* __restrict__ o)
{
    const int blk = blockIdx.x;          // 2*48*6 = 576
    const int t = threadIdx.x;
    const int bx = blk % 6;
    const int rem = blk / 6;
    const int y = rem % HH, b = rem / HH;
    const int x0 = bx * 8;

    __shared__ float vl[3][10][CC];      // 23.0 KB
    __shared__ float pa[8][FF];          // 15.6 KB

    // v patch: rows y-1..y+1, cols x0-1..x0+8 -> 30 positions x 48 float4
    for (int i = t; i < 30 * 48; i += 256) {
        const int pos = i / 48, c4 = i % 48;
        const int ry = pos / 10, rx = pos % 10;
        const int gy = y + ry - 1, gx = x0 + rx - 1;
        float4 val = make_float4(0.f, 0.f, 0.f, 0.f);
        if (gy >= 0 && gy < HH && gx >= 0 && gx < WW)
            val = *(const float4*)(v + ((size_t)(b * HH + gy) * WW + gx) * CC + c4 * 4);
        *(float4*)(&vl[ry][rx][c4 * 4]) = val;
    }
    // logits: 8 pixels x 243 float2
    const int nbase = (b * HH + y) * WW + x0;
    for (int i = t; i < 8 * 243; i += 256) {
        const int px = i / 243, c2 = i % 243;
        *(float2*)(&pa[px][c2 * 2]) = *(const float2*)(a + (size_t)(nbase + px) * FF + c2 * 2);
    }
    __syncthreads();

    // softmax: 8 * 54 = 432 rows of 9
    for (int r = t; r < 432; r += 256) {
        const int px = r / 54, hr = r % 54;
        float* row = &pa[px][hr * 9];
        float tv[KK];
        float m = -1e30f;
        #pragma unroll
        for (int j = 0; j < KK; ++j) { tv[j] = row[j] * SCALE; m = fmaxf(m, tv[j]); }
        float s = 0.f;
        #pragma unroll
        for (int j = 0; j < KK; ++j) { tv[j] = __expf(tv[j] - m); s += tv[j]; }
        const float inv = 1.f / s;
        #pragma unroll
        for (int j = 0; j < KK; ++j) row[j] = tv[j] * inv;
    }
    __syncthreads();

    // out: per pixel 9 taps x 192 ch = 1728 values
    for (int px = 0; px < 8; ++px) {
        float* ob = o + (size_t)(nbase + px) * KK * CC;
        #pragma unroll
        for (int r = 0; r < 7; ++r) {
            const int idx = r * 256 + t;
            if (idx < KK * CC) {
                const int i = idx / CC, c = idx % CC;
                const float* ph = &pa[px][(c / HD) * 81 + i * 9];
                float acc = 0.f;
                #pragma unroll
                for (int j = 0; j < KK; ++j)
                    acc += ph[j] * vl[j / 3][px + j % 3][c];
                ob[idx] = acc;
            }
        }
    }
}

// ---------------------------------------------------------------------------
// proj with fused fold: A-tile staged by 9-tap gather from o, then MFMA GEMM.
// BM=BN=64, grid (72, 3), whole K=192 in LDS.
// ---------------------------------------------------------------------------
__global__ __launch_bounds__(256) void proj_fold_kernel(
    const float* __restrict__ o, const float* __restrict__ pw,
    const float* __restrict__ pb, float* __restrict__ out)
{
    __shared__ bf16 As[64][LDA];
    __shared__ bf16 Bs[64][LDA];
    const int t = threadIdx.x;
    const int m0 = blockIdx.x * 64;
    const int n0 = blockIdx.y * 64;

    // stage A: fold-gather. 64 rows x 48 float4, 12 per thread.
    #pragma unroll
    for (int i = 0; i < 12; ++i) {
        const int f = t + i * 256;
        const int row = f / 48, c4 = f % 48;
        const int n = m0 + row;
        const int b = n / (HH * WW), r2 = n % (HH * WW), y = r2 / WW, x = r2 % WW;
        float4 s = make_float4(0.f, 0.f, 0.f, 0.f);
        #pragma unroll
        for (int ki = 0; ki < 3; ++ki) {
            const int gy = y + 1 - ki;
            if (gy < 0 || gy >= HH) continue;
            #pragma unroll
            for (int kj = 0; kj < 3; ++kj) {
                const int gx = x + 1 - kj;
                if (gx < 0 || gx >= WW) continue;
                const float4 ov = *(const float4*)(
                    o + (((size_t)(b * HH + gy) * WW + gx) * KK + ki * 3 + kj) * CC + c4 * 4);
                s.x += ov.x; s.y += ov.y; s.z += ov.z; s.w += ov.w;
            }
        }
        bf16x4 tv = { (__bf16)s.x, (__bf16)s.y, (__bf16)s.z, (__bf16)s.w };
        *(bf16x4*)(&As[row][c4 * 4]) = tv;
    }
    // stage B: 64 rows x 48 float4
    #pragma unroll
    for (int i = 0; i < 12; ++i) {
        const int f = t + i * 256;
        const int row = f / 48, c4 = f % 48;
        const float4 wv = *(const float4*)(pw + (size_t)(n0 + row) * KD + c4 * 4);
        bf16x4 tv = { (__bf16)wv.x, (__bf16)wv.y, (__bf16)wv.z, (__bf16)wv.w };
        *(bf16x4*)(&Bs[row][c4 * 4]) = tv;
    }
    __syncthreads();

    // 4 waves as 2x2 of 32x32 tiles
    const int wave = t >> 6, lane = t & 63;
    const int wm = (wave >> 1) * 32;
    const int wn = (wave & 1) * 32;
    const int lrow = lane & 15;
    const int lk   = (lane >> 4) * 8;

    f32x4 acc[2][2] = {};
    #pragma unroll
    for (int ks = 0; ks < 6; ++ks) {
        bf16x8 afr[2], bfr[2];
        #pragma unroll
        for (int j = 0; j < 2; ++j) {
            afr[j] = *(const bf16x8*)(&As[wm + j * 16 + lrow][ks * 32 + lk]);
            bfr[j] = *(const bf16x8*)(&Bs[wn + j * 16 + lrow][ks * 32 + lk]);
        }
        #pragma unroll
        for (int i = 0; i < 2; ++i)
            #pragma unroll
            for (int j = 0; j < 2; ++j)
                acc[i][j] = __builtin_amdgcn_mfma_f32_16x16x32_bf16(afr[i], bfr[j], acc[i][j], 0, 0, 0);
    }

    const int crow = (lane >> 4) * 4;
    #pragma unroll
    for (int j = 0; j < 2; ++j) {
        const int col = n0 + wn + j * 16 + lrow;   // < 192 always
        const float bv = pb[col];
        #pragma unroll
        for (int i = 0; i < 2; ++i) {
            #pragma unroll
            for (int r = 0; r < 4; ++r) {
                const int row = m0 + wm + i * 16 + crow + r;
                out[(size_t)row * CC + col] = acc[i][j][r] + bv;
            }
        }
    }
}

extern "C" void kernel_launch(void* const* d_in, const int* in_sizes, int n_in,
                              void* d_out, int out_size, void* d_ws, size_t ws_size,
                              hipStream_t stream) {
    const float* x   = (const float*)d_in[0];
    const float* vw  = (const float*)d_in[1];
    const float* aw  = (const float*)d_in[2];
    const float* ab  = (const float*)d_in[3];
    const float* pw  = (const float*)d_in[4];
    const float* pb  = (const float*)d_in[5];
    float* out = (float*)d_out;

    float* v = (float*)d_ws;                 // NPIX*CC
    float* a = v + (size_t)NPIX * CC;        // NPIX*FF
    float* o = a + (size_t)NPIX * FF;        // NPIX*KK*CC

    dim3 blk(256);
    dim3 grid_va(NPIX / BM, 3 + 8);          // 36 x 11
    dim3 grid_pj(NPIX / 64, CC / 64);        // 72 x 3

    gemm_va_kernel<<<grid_va, blk, 0, stream>>>(x, vw, aw, ab, v, a);
    attn8_kernel<<<2 * HH * (WW / 8), blk, 0, stream>>>(v, a, o);
    proj_fold_kernel<<<grid_pj, blk, 0, stream>>>(o, pw, pb, out);
}

// Round 9
// 116.536 us; speedup vs baseline: 1.1922x; 1.1922x over previous
//
#include <hip/hip_runtime.h>

#define BB 2
#define HH 48
#define WW 48
#define CC 192
#define NHEADS 6
#define HD 32
#define KK 9
#define FF 486
#define NPIX (BB*HH*WW)   // 4608
#define SCALE 0.17677669529663687f  // 1/sqrt(32)

typedef __bf16 bf16;
typedef __attribute__((ext_vector_type(4))) __bf16 bf16x4;
typedef __attribute__((ext_vector_type(8))) __bf16 bf16x8;
typedef __attribute__((ext_vector_type(4))) float f32x4;

#define KD 192
#define LDA 200   // padded LDS row stride in bf16

// ---------------------------------------------------------------------------
// gemm_va: 64x64 tiles, grid (72, 11) = 792 blocks (3.1 blocks/CU).
// v = x@vw^T (by<3), a = x@aw^T + ab (by>=3). 4 waves as 2x2 of 32x32.
// ---------------------------------------------------------------------------
__global__ __launch_bounds__(256) void gemm_va_kernel(
    const float* __restrict__ x, const float* __restrict__ vw,
    const float* __restrict__ aw, const float* __restrict__ ab,
    float* __restrict__ v, float* __restrict__ a)
{
    __shared__ bf16 As[64][LDA];
    __shared__ bf16 Bs[64][LDA];
    const int t = threadIdx.x;
    const int m0 = blockIdx.x * 64;
    const int by = blockIdx.y;
    const bool is_v = (by < 3);
    const int n0 = is_v ? by * 64 : (by - 3) * 64;
    const int Ndim = is_v ? CC : FF;
    const float* W = is_v ? vw : aw;
    float* OUT = is_v ? v : a;

    // stage A: 64 x 192, 12 float4/thread
    #pragma unroll
    for (int i = 0; i < 12; ++i) {
        const int f = t + i * 256;
        const int row = f / 48, c4 = f % 48;
        const float4 xv = *(const float4*)(x + (size_t)(m0 + row) * KD + c4 * 4);
        bf16x4 tv = { (__bf16)xv.x, (__bf16)xv.y, (__bf16)xv.z, (__bf16)xv.w };
        *(bf16x4*)(&As[row][c4 * 4]) = tv;
    }
    // stage B: 64 x 192 with row bound (FF tail)
    #pragma unroll
    for (int i = 0; i < 12; ++i) {
        const int f = t + i * 256;
        const int row = f / 48, c4 = f % 48;
        float4 wv = make_float4(0.f, 0.f, 0.f, 0.f);
        if (n0 + row < Ndim)
            wv = *(const float4*)(W + (size_t)(n0 + row) * KD + c4 * 4);
        bf16x4 tv = { (__bf16)wv.x, (__bf16)wv.y, (__bf16)wv.z, (__bf16)wv.w };
        *(bf16x4*)(&Bs[row][c4 * 4]) = tv;
    }
    __syncthreads();

    const int wave = t >> 6, lane = t & 63;
    const int wm = (wave >> 1) * 32;
    const int wn = (wave & 1) * 32;
    const int lrow = lane & 15;
    const int lk   = (lane >> 4) * 8;

    f32x4 acc[2][2] = {};
    #pragma unroll
    for (int ks = 0; ks < 6; ++ks) {
        bf16x8 afr[2], bfr[2];
        #pragma unroll
        for (int j = 0; j < 2; ++j) {
            afr[j] = *(const bf16x8*)(&As[wm + j * 16 + lrow][ks * 32 + lk]);
            bfr[j] = *(const bf16x8*)(&Bs[wn + j * 16 + lrow][ks * 32 + lk]);
        }
        #pragma unroll
        for (int i = 0; i < 2; ++i)
            #pragma unroll
            for (int j = 0; j < 2; ++j)
                acc[i][j] = __builtin_amdgcn_mfma_f32_16x16x32_bf16(afr[i], bfr[j], acc[i][j], 0, 0, 0);
    }

    const int crow = (lane >> 4) * 4;
    #pragma unroll
    for (int j = 0; j < 2; ++j) {
        const int col = n0 + wn + j * 16 + lrow;
        if (col < Ndim) {
            const float bv = is_v ? 0.f : ab[col];
            #pragma unroll
            for (int i = 0; i < 2; ++i) {
                #pragma unroll
                for (int r = 0; r < 4; ++r) {
                    const int row = m0 + wm + i * 16 + crow + r;
                    OUT[(size_t)row * Ndim + col] = acc[i][j][r] + bv;
                }
            }
        }
    }
}

// ---------------------------------------------------------------------------
// attn: one 192-thread block per pixel (round-6 version, 4608 blocks).
// ---------------------------------------------------------------------------
__global__ void attn_kernel(const float* __restrict__ v, const float* __restrict__ a,
                            float* __restrict__ o) {
    int n = blockIdx.x;
    int tid = threadIdx.x; // 0..191
    int b = n / (HH * WW), rem = n % (HH * WW), h = rem / WW, w = rem % WW;
    __shared__ float p[FF];
    __shared__ float vl[KK][CC];

    for (int f = tid; f < FF; f += CC) p[f] = a[n * FF + f];
    #pragma unroll
    for (int j = 0; j < KK; ++j) {
        int hh = h + j / 3 - 1, ww = w + j % 3 - 1;
        if (hh >= 0 && hh < HH && ww >= 0 && ww < WW)
            vl[j][tid] = v[((b * HH + hh) * WW + ww) * CC + tid];
        else
            vl[j][tid] = 0.f;
    }
    __syncthreads();

    if (tid < NHEADS * KK) {
        float* row = p + tid * KK;
        float t[KK];
        float m = -1e30f;
        #pragma unroll
        for (int j = 0; j < KK; ++j) { t[j] = row[j] * SCALE; m = fmaxf(m, t[j]); }
        float s = 0.f;
        #pragma unroll
        for (int j = 0; j < KK; ++j) { t[j] = __expf(t[j] - m); s += t[j]; }
        float inv = 1.f / s;
        #pragma unroll
        for (int j = 0; j < KK; ++j) row[j] = t[j] * inv;
    }
    __syncthreads();

    int head = tid / HD;
    const float* ph = p + head * 81;
    #pragma unroll
    for (int i = 0; i < KK; ++i) {
        float acc = 0.f;
        #pragma unroll
        for (int j = 0; j < KK; ++j) acc += ph[i * 9 + j] * vl[j][tid];
        o[(n * KK + i) * CC + tid] = acc;
    }
}

// ---------------------------------------------------------------------------
// proj with fused fold: BM=32, grid (144, 3) = 432 blocks.
// A-tile staged by 9-tap fold-gather from o; 4 waves cover 32x64 as 2x2 16x32.
// ---------------------------------------------------------------------------
__global__ __launch_bounds__(256) void proj_fold_kernel(
    const float* __restrict__ o, const float* __restrict__ pw,
    const float* __restrict__ pb, float* __restrict__ out)
{
    __shared__ bf16 As[32][LDA];
    __shared__ bf16 Bs[64][LDA];
    const int t = threadIdx.x;
    const int m0 = blockIdx.x * 32;
    const int n0 = blockIdx.y * 64;

    // stage A: fold-gather, 32 rows x 48 float4 = 1536, 6 per thread (not unrolled)
    for (int i = 0; i < 6; ++i) {
        const int f = t + i * 256;
        const int row = f / 48, c4 = f % 48;
        const int n = m0 + row;
        const int b = n / (HH * WW), r2 = n % (HH * WW), y = r2 / WW, x = r2 % WW;
        float4 s = make_float4(0.f, 0.f, 0.f, 0.f);
        for (int ki = 0; ki < 3; ++ki) {
            const int gy = y + 1 - ki;
            if (gy < 0 || gy >= HH) continue;
            for (int kj = 0; kj < 3; ++kj) {
                const int gx = x + 1 - kj;
                if (gx < 0 || gx >= WW) continue;
                const float4 ov = *(const float4*)(
                    o + (((size_t)(b * HH + gy) * WW + gx) * KK + ki * 3 + kj) * CC + c4 * 4);
                s.x += ov.x; s.y += ov.y; s.z += ov.z; s.w += ov.w;
            }
        }
        bf16x4 tv = { (__bf16)s.x, (__bf16)s.y, (__bf16)s.z, (__bf16)s.w };
        *(bf16x4*)(&As[row][c4 * 4]) = tv;
    }
    // stage B: 64 rows x 48 float4, 12 per thread (always in-bounds, CC=192)
    #pragma unroll
    for (int i = 0; i < 12; ++i) {
        const int f = t + i * 256;
        const int row = f / 48, c4 = f % 48;
        const float4 wv = *(const float4*)(pw + (size_t)(n0 + row) * KD + c4 * 4);
        bf16x4 tv = { (__bf16)wv.x, (__bf16)wv.y, (__bf16)wv.z, (__bf16)wv.w };
        *(bf16x4*)(&Bs[row][c4 * 4]) = tv;
    }
    __syncthreads();

    const int wave = t >> 6, lane = t & 63;
    const int wm = (wave & 1) * 16;     // 0/16
    const int wn = (wave >> 1) * 32;    // 0/32
    const int lrow = lane & 15;
    const int lk   = (lane >> 4) * 8;

    f32x4 acc[2] = {};
    #pragma unroll
    for (int ks = 0; ks < 6; ++ks) {
        bf16x8 afr = *(const bf16x8*)(&As[wm + lrow][ks * 32 + lk]);
        #pragma unroll
        for (int j = 0; j < 2; ++j) {
            bf16x8 bfr = *(const bf16x8*)(&Bs[wn + j * 16 + lrow][ks * 32 + lk]);
            acc[j] = __builtin_amdgcn_mfma_f32_16x16x32_bf16(afr, bfr, acc[j], 0, 0, 0);
        }
    }

    const int crow = (lane >> 4) * 4;
    #pragma unroll
    for (int j = 0; j < 2; ++j) {
        const int col = n0 + wn + j * 16 + lrow;   // < 192 always
        const float bv = pb[col];
        #pragma unroll
        for (int r = 0; r < 4; ++r) {
            const int row = m0 + wm + crow + r;
            out[(size_t)row * CC + col] = acc[j][r] + bv;
        }
    }
}

extern "C" void kernel_launch(void* const* d_in, const int* in_sizes, int n_in,
                              void* d_out, int out_size, void* d_ws, size_t ws_size,
                              hipStream_t stream) {
    const float* x   = (const float*)d_in[0];
    const float* vw  = (const float*)d_in[1];
    const float* aw  = (const float*)d_in[2];
    const float* ab  = (const float*)d_in[3];
    const float* pw  = (const float*)d_in[4];
    const float* pb  = (const float*)d_in[5];
    float* out = (float*)d_out;

    float* v = (float*)d_ws;                 // NPIX*CC
    float* a = v + (size_t)NPIX * CC;        // NPIX*FF
    float* o = a + (size_t)NPIX * FF;        // NPIX*KK*CC

    dim3 blk(256);
    dim3 grid_va(NPIX / 64, 3 + 8);          // 72 x 11 = 792 blocks
    dim3 grid_pj(NPIX / 32, CC / 64);        // 144 x 3 = 432 blocks

    gemm_va_kernel<<<grid_va, blk, 0, stream>>>(x, vw, aw, ab, v, a);
    attn_kernel<<<NPIX, CC, 0, stream>>>(v, a, o);
    proj_fold_kernel<<<grid_pj, blk, 0, stream>>>(o, pw, pb, out);
}

// Round 11
// 104.454 us; speedup vs baseline: 1.3301x; 1.1157x over previous
//
#include <hip/hip_runtime.h>

#define BB 2
#define HH 48
#define WW 48
#define CC 192
#define NHEADS 6
#define HD 32
#define KK 9
#define FF 486
#define NPIX (BB*HH*WW)   // 4608
#define SCALE 0.17677669529663687f  // 1/sqrt(32)

typedef __bf16 bf16;
typedef __attribute__((ext_vector_type(2))) __bf16 bf16x2;
typedef __attribute__((ext_vector_type(4))) __bf16 bf16x4;
typedef __attribute__((ext_vector_type(8))) __bf16 bf16x8;
typedef __attribute__((ext_vector_type(4))) float f32x4;

#define KD 192
#define LDA 200   // padded LDS row stride in bf16 (400 B)

// ---------------------------------------------------------------------------
// gemm_va: 64x64 tiles, grid (72, 11) = 792 blocks.
// v = x@vw^T -> bf16 out;  a = x@aw^T + ab -> fp32 out.
// ---------------------------------------------------------------------------
__global__ __launch_bounds__(256) void gemm_va_kernel(
    const float* __restrict__ x, const float* __restrict__ vw,
    const float* __restrict__ aw, const float* __restrict__ ab,
    bf16* __restrict__ v, float* __restrict__ a)
{
    __shared__ bf16 As[64][LDA];
    __shared__ bf16 Bs[64][LDA];
    const int t = threadIdx.x;
    const int m0 = blockIdx.x * 64;
    const int by = blockIdx.y;
    const bool is_v = (by < 3);
    const int n0 = is_v ? by * 64 : (by - 3) * 64;
    const int Ndim = is_v ? CC : FF;
    const float* W = is_v ? vw : aw;

    #pragma unroll
    for (int i = 0; i < 12; ++i) {
        const int f = t + i * 256;
        const int row = f / 48, c4 = f % 48;
        const float4 xv = *(const float4*)(x + (size_t)(m0 + row) * KD + c4 * 4);
        bf16x4 tv = { (__bf16)xv.x, (__bf16)xv.y, (__bf16)xv.z, (__bf16)xv.w };
        *(bf16x4*)(&As[row][c4 * 4]) = tv;
    }
    #pragma unroll
    for (int i = 0; i < 12; ++i) {
        const int f = t + i * 256;
        const int row = f / 48, c4 = f % 48;
        float4 wv = make_float4(0.f, 0.f, 0.f, 0.f);
        if (n0 + row < Ndim)
            wv = *(const float4*)(W + (size_t)(n0 + row) * KD + c4 * 4);
        bf16x4 tv = { (__bf16)wv.x, (__bf16)wv.y, (__bf16)wv.z, (__bf16)wv.w };
        *(bf16x4*)(&Bs[row][c4 * 4]) = tv;
    }
    __syncthreads();

    const int wave = t >> 6, lane = t & 63;
    const int wm = (wave >> 1) * 32;
    const int wn = (wave & 1) * 32;
    const int lrow = lane & 15;
    const int lk   = (lane >> 4) * 8;

    f32x4 acc[2][2] = {};
    #pragma unroll
    for (int ks = 0; ks < 6; ++ks) {
        bf16x8 afr[2], bfr[2];
        #pragma unroll
        for (int j = 0; j < 2; ++j) {
            afr[j] = *(const bf16x8*)(&As[wm + j * 16 + lrow][ks * 32 + lk]);
            bfr[j] = *(const bf16x8*)(&Bs[wn + j * 16 + lrow][ks * 32 + lk]);
        }
        #pragma unroll
        for (int i = 0; i < 2; ++i)
            #pragma unroll
            for (int j = 0; j < 2; ++j)
                acc[i][j] = __builtin_amdgcn_mfma_f32_16x16x32_bf16(afr[i], bfr[j], acc[i][j], 0, 0, 0);
    }

    const int crow = (lane >> 4) * 4;
    if (is_v) {
        #pragma unroll
        for (int j = 0; j < 2; ++j) {
            const int col = n0 + wn + j * 16 + lrow;   // < 192 always
            #pragma unroll
            for (int i = 0; i < 2; ++i)
                #pragma unroll
                for (int r = 0; r < 4; ++r) {
                    const int row = m0 + wm + i * 16 + crow + r;
                    v[(size_t)row * CC + col] = (__bf16)acc[i][j][r];
                }
        }
    } else {
        #pragma unroll
        for (int j = 0; j < 2; ++j) {
            const int col = n0 + wn + j * 16 + lrow;
            if (col < FF) {
                const float bv = ab[col];
                #pragma unroll
                for (int i = 0; i < 2; ++i)
                    #pragma unroll
                    for (int r = 0; r < 4; ++r) {
                        const int row = m0 + wm + i * 16 + crow + r;
                        a[(size_t)row * FF + col] = acc[i][j][r] + bv;
                    }
            }
        }
    }
}

// ---------------------------------------------------------------------------
// attn: one 192-thread block per pixel (4608 blocks). v bf16 in, o bf16 out.
// ---------------------------------------------------------------------------
__global__ void attn_kernel(const bf16* __restrict__ v, const float* __restrict__ a,
                            bf16* __restrict__ o) {
    int n = blockIdx.x;
    int tid = threadIdx.x; // 0..191
    int b = n / (HH * WW), rem = n % (HH * WW), h = rem / WW, w = rem % WW;
    __shared__ float p[FF];
    __shared__ float vl[KK][CC];

    for (int f = tid; f < FF; f += CC) p[f] = a[n * FF + f];
    #pragma unroll
    for (int j = 0; j < KK; ++j) {
        int hh = h + j / 3 - 1, ww = w + j % 3 - 1;
        if (hh >= 0 && hh < HH && ww >= 0 && ww < WW)
            vl[j][tid] = (float)v[((size_t)(b * HH + hh) * WW + ww) * CC + tid];
        else
            vl[j][tid] = 0.f;
    }
    __syncthreads();

    if (tid < NHEADS * KK) {
        float* row = p + tid * KK;
        float t[KK];
        float m = -1e30f;
        #pragma unroll
        for (int j = 0; j < KK; ++j) { t[j] = row[j] * SCALE; m = fmaxf(m, t[j]); }
        float s = 0.f;
        #pragma unroll
        for (int j = 0; j < KK; ++j) { t[j] = __expf(t[j] - m); s += t[j]; }
        float inv = 1.f / s;
        #pragma unroll
        for (int j = 0; j < KK; ++j) row[j] = t[j] * inv;
    }
    __syncthreads();

    int head = tid / HD;
    const float* ph = p + head * 81;
    #pragma unroll
    for (int i = 0; i < KK; ++i) {
        float acc = 0.f;
        #pragma unroll
        for (int j = 0; j < KK; ++j) acc += ph[i * 9 + j] * vl[j][tid];
        o[((size_t)n * KK + i) * CC + tid] = (__bf16)acc;
    }
}

// ---------------------------------------------------------------------------
// fold: linear, 2 channels (bf16x2) per thread. grid 1728 x 256.
// ---------------------------------------------------------------------------
__global__ void fold_kernel(const bf16x2* __restrict__ o, bf16x2* __restrict__ folded) {
    const int idx = blockIdx.x * blockDim.x + threadIdx.x;   // NPIX*96
    const int c2 = idx % 96, n = idx / 96;
    const int b = n / (HH * WW), rem = n % (HH * WW), y = rem / WW, x = rem % WW;
    float s0 = 0.f, s1 = 0.f;
    #pragma unroll
    for (int ki = 0; ki < 3; ++ki) {
        const int gy = y + 1 - ki;
        if (gy < 0 || gy >= HH) continue;
        #pragma unroll
        for (int kj = 0; kj < 3; ++kj) {
            const int gx = x + 1 - kj;
            if (gx < 0 || gx >= WW) continue;
            const size_t ps = (size_t)(b * HH + gy) * WW + gx;
            const bf16x2 ov = o[(ps * KK + ki * 3 + kj) * 96 + c2];
            s0 += (float)ov.x; s1 += (float)ov.y;
        }
    }
    bf16x2 r = { (__bf16)s0, (__bf16)s1 };
    folded[(size_t)n * 96 + c2] = r;
}

// ---------------------------------------------------------------------------
// proj: BM=32, grid (144, 3) = 432 blocks. A = straight bf16 copy from folded.
// ---------------------------------------------------------------------------
__global__ __launch_bounds__(256) void proj_kernel(
    const bf16* __restrict__ folded, const float* __restrict__ pw,
    const float* __restrict__ pb, float* __restrict__ out)
{
    __shared__ bf16 As[32][LDA];
    __shared__ bf16 Bs[64][LDA];
    const int t = threadIdx.x;
    const int m0 = blockIdx.x * 32;
    const int n0 = blockIdx.y * 64;

    // stage A: 32 rows x 24 chunks of bf16x8, 3 per thread
    #pragma unroll
    for (int i = 0; i < 3; ++i) {
        const int f = t + i * 256;
        const int row = f / 24, c8 = f % 24;
        const bf16x8 av = *(const bf16x8*)(folded + (size_t)(m0 + row) * KD + c8 * 8);
        *(bf16x8*)(&As[row][c8 * 8]) = av;
    }
    // stage B: 64 rows x 48 float4, 12 per thread
    #pragma unroll
    for (int i = 0; i < 12; ++i) {
        const int f = t + i * 256;
        const int row = f / 48, c4 = f % 48;
        const float4 wv = *(const float4*)(pw + (size_t)(n0 + row) * KD + c4 * 4);
        bf16x4 tv = { (__bf16)wv.x, (__bf16)wv.y, (__bf16)wv.z, (__bf16)wv.w };
        *(bf16x4*)(&Bs[row][c4 * 4]) = tv;
    }
    __syncthreads();

    const int wave = t >> 6, lane = t & 63;
    const int wm = (wave & 1) * 16;     // 0/16
    const int wn = (wave >> 1) * 32;    // 0/32
    const int lrow = lane & 15;
    const int lk   = (lane >> 4) * 8;

    f32x4 acc[2] = {};
    #pragma unroll
    for (int ks = 0; ks < 6; ++ks) {
        bf16x8 afr = *(const bf16x8*)(&As[wm + lrow][ks * 32 + lk]);
        #pragma unroll
        for (int j = 0; j < 2; ++j) {
            bf16x8 bfr = *(const bf16x8*)(&Bs[wn + j * 16 + lrow][ks * 32 + lk]);
            acc[j] = __builtin_amdgcn_mfma_f32_16x16x32_bf16(afr, bfr, acc[j], 0, 0, 0);
        }
    }

    const int crow = (lane >> 4) * 4;
    #pragma unroll
    for (int j = 0; j < 2; ++j) {
        const int col = n0 + wn + j * 16 + lrow;   // < 192 always
        const float bv = pb[col];
        #pragma unroll
        for (int r = 0; r < 4; ++r) {
            const int row = m0 + wm + crow + r;
            out[(size_t)row * CC + col] = acc[j][r] + bv;
        }
    }
}

extern "C" void kernel_launch(void* const* d_in, const int* in_sizes, int n_in,
                              void* d_out, int out_size, void* d_ws, size_t ws_size,
                              hipStream_t stream) {
    const float* x   = (const float*)d_in[0];
    const float* vw  = (const float*)d_in[1];
    const float* aw  = (const float*)d_in[2];
    const float* ab  = (const float*)d_in[3];
    const float* pw  = (const float*)d_in[4];
    const float* pb  = (const float*)d_in[5];
    float* out = (float*)d_out;

    // ws layout: a (fp32), then bf16 v / o / folded
    float* a      = (float*)d_ws;                          // NPIX*FF fp32
    bf16* v       = (bf16*)(a + (size_t)NPIX * FF);        // NPIX*CC bf16
    bf16* o       = v + (size_t)NPIX * CC;                 // NPIX*KK*CC bf16
    bf16* folded  = o + (size_t)NPIX * KK * CC;            // NPIX*CC bf16

    dim3 blk(256);
    dim3 grid_va(NPIX / 64, 3 + 8);          // 72 x 11 = 792 blocks
    dim3 grid_pj(NPIX / 32, CC / 64);        // 144 x 3 = 432 blocks

    gemm_va_kernel<<<grid_va, blk, 0, stream>>>(x, vw, aw, ab, v, a);
    attn_kernel<<<NPIX, CC, 0, stream>>>(v, a, o);
    fold_kernel<<<(NPIX * 96) / 256, blk, 0, stream>>>((const bf16x2*)o, (bf16x2*)folded);
    proj_kernel<<<grid_pj, blk, 0, stream>>>(folded, pw, pb, out);
}